// Round 9
// baseline (180.390 us; speedup 1.0000x reference)
//
#include <hip/hip_runtime.h>
#include <math.h>

#define EMBED 384
#define HID 64
#define NE 4
#define TPB 1024
#define MT 8                  // tokens per 16-lane group
#define JS 16                 // lanes per token group
#define JPT 4                 // hidden units per lane
#define TOKB 512              // tokens per block

// LDS floats: wln[384*64] + w2s[256] + c1s[64] + c2s[64] + part[2*1024] + red[8]
#define WLN_F   (EMBED * HID)           // 24576
#define W2_OFF  (WLN_F)                 // +256
#define C1_OFF  (W2_OFF + HID * NE)     // +64
#define C2_OFF  (C1_OFF + HID)          // +64
#define PART_OFF (C2_OFF + HID)         // +2048
#define RED_OFF (PART_OFF + 2 * TPB)    // +8
#define SMEM_FLOATS (RED_OFF + 2 * NE)  // ~105.6 KB

__global__ void
__attribute__((amdgpu_flat_work_group_size(TPB, TPB), amdgpu_waves_per_eu(4, 4)))
router_main(
    const float* __restrict__ x, const float* __restrict__ lnw,
    const float* __restrict__ lnb, const float* __restrict__ w1,
    const float* __restrict__ w2, float* __restrict__ out,
    float* __restrict__ ws, int ntok)
{
  extern __shared__ float smem[];
  float* wln = smem;
  float* w2s = smem + W2_OFF;
  float* c1s = smem + C1_OFF;
  float* c2s = smem + C2_OFF;
  float* part = smem + PART_OFF;
  float* red = smem + RED_OFF;

  const int tid = (int)threadIdx.x;

  // ---- stage wln = lnw[d] * w1[d][j] into LDS (6 float4 / thread) ----
  {
    const float4* src = reinterpret_cast<const float4*>(w1);
    float4* dst = reinterpret_cast<float4*>(wln);
    #pragma unroll
    for (int k = 0; k < (WLN_F / 4) / TPB; ++k) {
      const int f4 = tid + k * TPB;
      const float sc = lnw[f4 >> 4];          // d = f4/16 (16 float4 per row)
      float4 v = src[f4];
      v.x *= sc; v.y *= sc; v.z *= sc; v.w *= sc;
      dst[f4] = v;
    }
  }
  if (tid < HID * NE / 4) {                   // stage w2 (64 float4)
    reinterpret_cast<float4*>(w2s)[tid] = reinterpret_cast<const float4*>(w2)[tid];
  }
  if (tid < 2 * NE) red[tid] = 0.f;
  __syncthreads();

  // ---- cooperative c1[j] = sum_d wln[d][j]; c2[j] = sum_d lnb[d]*w1[d][j] ----
  {
    const int j = tid & 63;
    const int dpart = tid >> 6;               // 16 parts x 24 d's
    float c1p = 0.f, c2p = 0.f;
    #pragma unroll 8
    for (int k = 0; k < EMBED / 16; ++k) {
      const int d = dpart * (EMBED / 16) + k;
      c1p += wln[d * HID + j];
      c2p = fmaf(lnb[d], w1[d * HID + j], c2p);
    }
    part[dpart * 64 + j] = c1p;
    part[TPB + dpart * 64 + j] = c2p;
  }
  __syncthreads();
  if (tid < HID) {
    float a = 0.f, b = 0.f;
    #pragma unroll
    for (int p = 0; p < 16; ++p) {
      a += part[p * 64 + tid];
      b += part[TPB + p * 64 + tid];
    }
    c1s[tid] = a;
    c2s[tid] = b;
  }
  __syncthreads();

  // ---- token/lane mapping ----
  const int lane = tid & 63;
  const int wv = tid >> 6;                    // 16 waves
  const int tg = lane >> 4;                   // 4 token groups / wave
  const int jg = lane & 15;                   // j-sixteenth
  const int wbase = (int)blockIdx.x * TOKB + wv * 32;
  const int t0 = wbase + tg * MT;             // this group's 8 tokens
  const int joff = jg * JPT;

  const float* __restrict__ xrow = x + (size_t)t0 * EMBED;
  const float* __restrict__ xown = x + (size_t)(t0 + (jg & 7)) * EMBED;

  // ---- fused single pass: own-token stats + GEMM1 ----
  float acc[MT][JPT];
  #pragma unroll
  for (int m = 0; m < MT; ++m)
    #pragma unroll
    for (int j = 0; j < JPT; ++j) acc[m][j] = 0.f;
  float s = 0.f, s2 = 0.f;                    // stats for token t0+(jg&7)

  for (int dq = 0; dq < EMBED / 4; ++dq) {
    const int d = dq * 4;

    // own-token stats (16-lane broadcast line, 2x redundant chip-wide)
    {
      float4 xo = *reinterpret_cast<const float4*>(xown + d);
      s += (xo.x + xo.y) + (xo.z + xo.w);
      s2 = fmaf(xo.x, xo.x, s2);
      s2 = fmaf(xo.y, xo.y, s2);
      s2 = fmaf(xo.z, xo.z, s2);
      s2 = fmaf(xo.w, xo.w, s2);
    }

    float4 xv[MT];
    #pragma unroll
    for (int m = 0; m < MT; ++m)
      xv[m] = *reinterpret_cast<const float4*>(xrow + (size_t)m * EMBED + d);

    #pragma unroll
    for (int dd = 0; dd < 4; ++dd) {
      const float4 wv4 = *reinterpret_cast<const float4*>(wln + (d + dd) * HID + joff);
      #pragma unroll
      for (int m = 0; m < MT; ++m) {
        const float xx = (dd == 0) ? xv[m].x : (dd == 1) ? xv[m].y
                       : (dd == 2) ? xv[m].z : xv[m].w;
        acc[m][0] = fmaf(xx, wv4.x, acc[m][0]);
        acc[m][1] = fmaf(xx, wv4.y, acc[m][1]);
        acc[m][2] = fmaf(xx, wv4.z, acc[m][2]);
        acc[m][3] = fmaf(xx, wv4.w, acc[m][3]);
      }
    }
  }

  // ---- own-token LN stats -> broadcast to group ----
  const float mu_own = s * (1.f / EMBED);
  const float var_own = fmaf(-mu_own, mu_own, s2 * (1.f / EMBED));
  const float rstd_own = rsqrtf(var_own + 1e-5f);

  const int gb = lane & ~15;                  // first lane of this 16-lane group
  float mu[MT], rstd[MT];
  #pragma unroll
  for (int m = 0; m < MT; ++m) {
    mu[m]   = __shfl(mu_own,   gb + m);
    rstd[m] = __shfl(rstd_own, gb + m);
  }

  // ---- epilogue: LN-correct, GELU, GEMM2 partials over 4 j's ----
  float logit[MT][NE];
  #pragma unroll
  for (int m = 0; m < MT; ++m)
    #pragma unroll
    for (int e = 0; e < NE; ++e) logit[m][e] = 0.f;

  #pragma unroll
  for (int jj = 0; jj < JPT; ++jj) {
    const int j = joff + jj;
    const float c1 = c1s[j];
    const float c2 = c2s[j];
    float4 wv = *reinterpret_cast<const float4*>(w2s + j * NE);
    #pragma unroll
    for (int m = 0; m < MT; ++m) {
      const float hid = fmaf(rstd[m], fmaf(-mu[m], c1, acc[m][jj]), c2);
      const float g = 0.5f * hid * (1.f + erff(hid * 0.7071067811865475f));
      logit[m][0] = fmaf(g, wv.x, logit[m][0]);
      logit[m][1] = fmaf(g, wv.y, logit[m][1]);
      logit[m][2] = fmaf(g, wv.z, logit[m][2]);
      logit[m][3] = fmaf(g, wv.w, logit[m][3]);
    }
  }

  // ---- reduce logits across the 16-lane group ----
  #pragma unroll
  for (int m = 0; m < MT; ++m)
    #pragma unroll
    for (int e = 0; e < NE; ++e) {
      logit[m][e] += __shfl_xor(logit[m][e], 1);
      logit[m][e] += __shfl_xor(logit[m][e], 2);
      logit[m][e] += __shfl_xor(logit[m][e], 4);
      logit[m][e] += __shfl_xor(logit[m][e], 8);
    }

  // lane with jg<8 owns token t0 + jg (jg>=8 lanes are duplicates, no store)
  const int mown = jg & 7;
  float l[NE];
  #pragma unroll
  for (int e = 0; e < NE; ++e) {
    float v = logit[0][e];
    v = (mown == 1) ? logit[1][e] : v;
    v = (mown == 2) ? logit[2][e] : v;
    v = (mown == 3) ? logit[3][e] : v;
    v = (mown == 4) ? logit[4][e] : v;
    v = (mown == 5) ? logit[5][e] : v;
    v = (mown == 6) ? logit[6][e] : v;
    v = (mown == 7) ? logit[7][e] : v;
    l[e] = v * 0.5f;                          // /T, T=2
  }
  const int mytok = t0 + mown;
  const bool owner = (jg < 8);

  const float mx = fmaxf(fmaxf(l[0], l[1]), fmaxf(l[2], l[3]));
  const float e0 = expf(l[0] - mx), e1 = expf(l[1] - mx),
              e2 = expf(l[2] - mx), e3 = expf(l[3] - mx);
  const float inv = 1.f / (e0 + e1 + e2 + e3);
  const float p0 = e0 * inv, p1 = e1 * inv, p2 = e2 * inv, p3 = e3 * inv;

  int best = 0; float bp = p0;
  if (p1 > bp) { bp = p1; best = 1; }
  if (p2 > bp) { bp = p2; best = 2; }
  if (p3 > bp) { bp = p3; best = 3; }

  if (owner && mytok < ntok) {
    *reinterpret_cast<float4*>(out + (size_t)mytok * 4) = make_float4(p0, p1, p2, p3);
    out[(size_t)ntok * 4 + mytok] = (float)best;
    float* o3 = out + (size_t)ntok * 5 + 1 + (size_t)mytok * 4;
    o3[0] = p0; o3[1] = p1; o3[2] = p2; o3[3] = p3;
  }

  // ---- aux reduction: wave -> LDS -> global (owners only contribute) ----
  const float wsc = owner ? 1.f : 0.f;
  float psum[NE] = {p0 * wsc, p1 * wsc, p2 * wsc, p3 * wsc};
  float pcnt[NE];
  pcnt[0] = (owner && best == 0) ? 1.f : 0.f;
  pcnt[1] = (owner && best == 1) ? 1.f : 0.f;
  pcnt[2] = (owner && best == 2) ? 1.f : 0.f;
  pcnt[3] = (owner && best == 3) ? 1.f : 0.f;

  #pragma unroll
  for (int e = 0; e < NE; ++e) {
    float a = psum[e], c = pcnt[e];
    #pragma unroll
    for (int off = 32; off; off >>= 1) {
      a += __shfl_xor(a, off);
      c += __shfl_xor(c, off);
    }
    if (lane == 0) {
      atomicAdd(&red[e], a);
      atomicAdd(&red[NE + e], c);
    }
  }
  __syncthreads();
  if (tid < 2 * NE) atomicAdd(&ws[tid], red[tid]);
}

__global__ void router_finalize(const float* __restrict__ ws,
                                float* __restrict__ out, int ntok)
{
  if (threadIdx.x == 0 && blockIdx.x == 0) {
    const float invN = 1.f / (float)ntok;
    float aux = 0.f;
    #pragma unroll
    for (int e = 0; e < NE; ++e)
      aux = fmaf(ws[NE + e] * invN, ws[e] * invN, aux);
    out[(size_t)ntok * 5] = (float)NE * aux;
  }
}

extern "C" void kernel_launch(void* const* d_in, const int* in_sizes, int n_in,
                              void* d_out, int out_size, void* d_ws, size_t ws_size,
                              hipStream_t stream) {
  const float* x   = (const float*)d_in[0];
  const float* lnw = (const float*)d_in[1];
  const float* lnb = (const float*)d_in[2];
  const float* w1  = (const float*)d_in[3];
  const float* w2  = (const float*)d_in[4];
  float* out = (float*)d_out;
  float* ws  = (float*)d_ws;

  const int ntok = in_sizes[0] / EMBED;   // 131072

  hipMemsetAsync(d_ws, 0, 2 * NE * sizeof(float), stream);

  const int blocks = (ntok + TOKB - 1) / TOKB;             // 256
  const size_t smem_bytes = SMEM_FLOATS * sizeof(float);   // ~105.6 KB
  router_main<<<blocks, TPB, smem_bytes, stream>>>(x, lnw, lnb, w1, w2, out, ws, ntok);
  router_finalize<<<1, 64, 0, stream>>>(ws, out, ntok);
}

// Round 10
// 176.844 us; speedup vs baseline: 1.0200x; 1.0200x over previous
//
#include <hip/hip_runtime.h>
#include <math.h>

#define EMBED 384
#define HID 64
#define NE 4
#define TPB 512
#define MT 8                  // tokens per 16-lane group
#define JS 16                 // lanes per token group
#define JPT 4                 // hidden units per lane
#define TOKB 256              // tokens per block (8 waves x 32 tokens)

// LDS floats: wln[384*64] + w2s[256] + c1s[64] + c2s[64] + part[2*512] + red[8]
#define WLN_F   (EMBED * HID)           // 24576
#define W2_OFF  (WLN_F)                 // +256
#define C1_OFF  (W2_OFF + HID * NE)     // +64
#define C2_OFF  (C1_OFF + HID)          // +64
#define PART_OFF (C2_OFF + HID)         // +1024
#define RED_OFF (PART_OFF + 2 * TPB)    // +8
#define SMEM_FLOATS (RED_OFF + 2 * NE)  // ~102 KB

__global__ void
__attribute__((amdgpu_flat_work_group_size(TPB, TPB), amdgpu_waves_per_eu(2, 2)))
router_main(
    const float* __restrict__ x, const float* __restrict__ lnw,
    const float* __restrict__ lnb, const float* __restrict__ w1,
    const float* __restrict__ w2, float* __restrict__ out,
    float* __restrict__ ws, int ntok)
{
  extern __shared__ float smem[];
  float* wln = smem;
  float* w2s = smem + W2_OFF;
  float* c1s = smem + C1_OFF;
  float* c2s = smem + C2_OFF;
  float* part = smem + PART_OFF;
  float* red = smem + RED_OFF;

  const int tid = (int)threadIdx.x;

  // ---- stage wln = lnw[d] * w1[d][j] into LDS (12 float4 / thread) ----
  {
    const float4* src = reinterpret_cast<const float4*>(w1);
    float4* dst = reinterpret_cast<float4*>(wln);
    #pragma unroll
    for (int k = 0; k < (WLN_F / 4) / TPB; ++k) {
      const int f4 = tid + k * TPB;
      const float sc = lnw[f4 >> 4];          // d = f4/16 (16 float4 per row)
      float4 v = src[f4];
      v.x *= sc; v.y *= sc; v.z *= sc; v.w *= sc;
      dst[f4] = v;
    }
  }
  if (tid < HID * NE / 4) {                   // stage w2 (64 float4)
    reinterpret_cast<float4*>(w2s)[tid] = reinterpret_cast<const float4*>(w2)[tid];
  }
  if (tid < 2 * NE) red[tid] = 0.f;
  __syncthreads();

  // ---- cooperative c1[j] = sum_d wln[d][j]; c2[j] = sum_d lnb[d]*w1[d][j] ----
  {
    const int j = tid & 63;
    const int dpart = tid >> 6;               // 8 parts x 48 d's
    float c1p = 0.f, c2p = 0.f;
    #pragma unroll 8
    for (int k = 0; k < EMBED / 8; ++k) {
      const int d = dpart * (EMBED / 8) + k;
      c1p += wln[d * HID + j];
      c2p = fmaf(lnb[d], w1[d * HID + j], c2p);
    }
    part[dpart * 64 + j] = c1p;
    part[TPB + dpart * 64 + j] = c2p;
  }
  __syncthreads();
  if (tid < HID) {
    float a = 0.f, b = 0.f;
    #pragma unroll
    for (int p = 0; p < 8; ++p) {
      a += part[p * 64 + tid];
      b += part[TPB + p * 64 + tid];
    }
    c1s[tid] = a;
    c2s[tid] = b;
  }
  __syncthreads();

  // ---- token/lane mapping ----
  const int lane = tid & 63;
  const int wv = tid >> 6;                    // 8 waves
  const int tg = lane >> 4;                   // 4 token groups / wave
  const int jg = lane & 15;                   // j-sixteenth
  const int wbase = (int)blockIdx.x * TOKB + wv * 32;
  const int t0 = wbase + tg * MT;             // this group's 8 tokens
  const int joff = jg * JPT;

  const float* __restrict__ xrow = x + (size_t)t0 * EMBED;
  const float* __restrict__ xown = x + (size_t)(t0 + (jg & 7)) * EMBED;

  // ---- fused single pass: own-token stats + GEMM1 ----
  float acc[MT][JPT];
  #pragma unroll
  for (int m = 0; m < MT; ++m)
    #pragma unroll
    for (int j = 0; j < JPT; ++j) acc[m][j] = 0.f;
  float s = 0.f, s2 = 0.f;                    // stats for token t0+(jg&7)

  for (int dq = 0; dq < EMBED / 4; ++dq) {
    const int d = dq * 4;

    // own-token stats (extra L1-hit load; same line as group's xv loads)
    {
      float4 xo = *reinterpret_cast<const float4*>(xown + d);
      s += (xo.x + xo.y) + (xo.z + xo.w);
      s2 = fmaf(xo.x, xo.x, s2);
      s2 = fmaf(xo.y, xo.y, s2);
      s2 = fmaf(xo.z, xo.z, s2);
      s2 = fmaf(xo.w, xo.w, s2);
    }

    float4 xv[MT];
    #pragma unroll
    for (int m = 0; m < MT; ++m)
      xv[m] = *reinterpret_cast<const float4*>(xrow + (size_t)m * EMBED + d);

    #pragma unroll
    for (int dd = 0; dd < 4; ++dd) {
      const float4 wv4 = *reinterpret_cast<const float4*>(wln + (d + dd) * HID + joff);
      #pragma unroll
      for (int m = 0; m < MT; ++m) {
        const float xx = (dd == 0) ? xv[m].x : (dd == 1) ? xv[m].y
                       : (dd == 2) ? xv[m].z : xv[m].w;
        acc[m][0] = fmaf(xx, wv4.x, acc[m][0]);
        acc[m][1] = fmaf(xx, wv4.y, acc[m][1]);
        acc[m][2] = fmaf(xx, wv4.z, acc[m][2]);
        acc[m][3] = fmaf(xx, wv4.w, acc[m][3]);
      }
    }
  }

  // ---- own-token LN stats -> broadcast to group ----
  const float mu_own = s * (1.f / EMBED);
  const float var_own = fmaf(-mu_own, mu_own, s2 * (1.f / EMBED));
  const float rstd_own = rsqrtf(var_own + 1e-5f);

  const int gb = lane & ~15;                  // first lane of this 16-lane group
  float mu[MT], rstd[MT];
  #pragma unroll
  for (int m = 0; m < MT; ++m) {
    mu[m]   = __shfl(mu_own,   gb + m);
    rstd[m] = __shfl(rstd_own, gb + m);
  }

  // ---- epilogue: LN-correct, GELU, GEMM2 partials over 4 j's ----
  float logit[MT][NE];
  #pragma unroll
  for (int m = 0; m < MT; ++m)
    #pragma unroll
    for (int e = 0; e < NE; ++e) logit[m][e] = 0.f;

  #pragma unroll
  for (int jj = 0; jj < JPT; ++jj) {
    const int j = joff + jj;
    const float c1 = c1s[j];
    const float c2 = c2s[j];
    float4 wv = *reinterpret_cast<const float4*>(w2s + j * NE);
    #pragma unroll
    for (int m = 0; m < MT; ++m) {
      const float hid = fmaf(rstd[m], fmaf(-mu[m], c1, acc[m][jj]), c2);
      const float g = 0.5f * hid * (1.f + erff(hid * 0.7071067811865475f));
      logit[m][0] = fmaf(g, wv.x, logit[m][0]);
      logit[m][1] = fmaf(g, wv.y, logit[m][1]);
      logit[m][2] = fmaf(g, wv.z, logit[m][2]);
      logit[m][3] = fmaf(g, wv.w, logit[m][3]);
    }
  }

  // ---- reduce logits across the 16-lane group ----
  #pragma unroll
  for (int m = 0; m < MT; ++m)
    #pragma unroll
    for (int e = 0; e < NE; ++e) {
      logit[m][e] += __shfl_xor(logit[m][e], 1);
      logit[m][e] += __shfl_xor(logit[m][e], 2);
      logit[m][e] += __shfl_xor(logit[m][e], 4);
      logit[m][e] += __shfl_xor(logit[m][e], 8);
    }

  // lanes jg<8 own token t0 + jg (jg>=8 lanes are duplicates, no store)
  const int mown = jg & 7;
  float l[NE];
  #pragma unroll
  for (int e = 0; e < NE; ++e) {
    float v = logit[0][e];
    v = (mown == 1) ? logit[1][e] : v;
    v = (mown == 2) ? logit[2][e] : v;
    v = (mown == 3) ? logit[3][e] : v;
    v = (mown == 4) ? logit[4][e] : v;
    v = (mown == 5) ? logit[5][e] : v;
    v = (mown == 6) ? logit[6][e] : v;
    v = (mown == 7) ? logit[7][e] : v;
    l[e] = v * 0.5f;                          // /T, T=2
  }
  const int mytok = t0 + mown;
  const bool owner = (jg < 8);

  const float mx = fmaxf(fmaxf(l[0], l[1]), fmaxf(l[2], l[3]));
  const float e0 = expf(l[0] - mx), e1 = expf(l[1] - mx),
              e2 = expf(l[2] - mx), e3 = expf(l[3] - mx);
  const float inv = 1.f / (e0 + e1 + e2 + e3);
  const float p0 = e0 * inv, p1 = e1 * inv, p2 = e2 * inv, p3 = e3 * inv;

  int best = 0; float bp = p0;
  if (p1 > bp) { bp = p1; best = 1; }
  if (p2 > bp) { bp = p2; best = 2; }
  if (p3 > bp) { bp = p3; best = 3; }

  if (owner && mytok < ntok) {
    *reinterpret_cast<float4*>(out + (size_t)mytok * 4) = make_float4(p0, p1, p2, p3);
    out[(size_t)ntok * 4 + mytok] = (float)best;
    float* o3 = out + (size_t)ntok * 5 + 1 + (size_t)mytok * 4;
    o3[0] = p0; o3[1] = p1; o3[2] = p2; o3[3] = p3;
  }

  // ---- aux reduction: wave -> LDS -> global (owners only contribute) ----
  const float wsc = owner ? 1.f : 0.f;
  float psum[NE] = {p0 * wsc, p1 * wsc, p2 * wsc, p3 * wsc};
  float pcnt[NE];
  pcnt[0] = (owner && best == 0) ? 1.f : 0.f;
  pcnt[1] = (owner && best == 1) ? 1.f : 0.f;
  pcnt[2] = (owner && best == 2) ? 1.f : 0.f;
  pcnt[3] = (owner && best == 3) ? 1.f : 0.f;

  #pragma unroll
  for (int e = 0; e < NE; ++e) {
    float a = psum[e], c = pcnt[e];
    #pragma unroll
    for (int off = 32; off; off >>= 1) {
      a += __shfl_xor(a, off);
      c += __shfl_xor(c, off);
    }
    if (lane == 0) {
      atomicAdd(&red[e], a);
      atomicAdd(&red[NE + e], c);
    }
  }
  __syncthreads();
  if (tid < 2 * NE) atomicAdd(&ws[tid], red[tid]);
}

__global__ void router_finalize(const float* __restrict__ ws,
                                float* __restrict__ out, int ntok)
{
  if (threadIdx.x == 0 && blockIdx.x == 0) {
    const float invN = 1.f / (float)ntok;
    float aux = 0.f;
    #pragma unroll
    for (int e = 0; e < NE; ++e)
      aux = fmaf(ws[NE + e] * invN, ws[e] * invN, aux);
    out[(size_t)ntok * 5] = (float)NE * aux;
  }
}

extern "C" void kernel_launch(void* const* d_in, const int* in_sizes, int n_in,
                              void* d_out, int out_size, void* d_ws, size_t ws_size,
                              hipStream_t stream) {
  const float* x   = (const float*)d_in[0];
  const float* lnw = (const float*)d_in[1];
  const float* lnb = (const float*)d_in[2];
  const float* w1  = (const float*)d_in[3];
  const float* w2  = (const float*)d_in[4];
  float* out = (float*)d_out;
  float* ws  = (float*)d_ws;

  const int ntok = in_sizes[0] / EMBED;   // 131072

  hipMemsetAsync(d_ws, 0, 2 * NE * sizeof(float), stream);

  const int blocks = (ntok + TOKB - 1) / TOKB;             // 512
  const size_t smem_bytes = SMEM_FLOATS * sizeof(float);   // ~102 KB
  router_main<<<blocks, TPB, smem_bytes, stream>>>(x, lnw, lnb, w1, w2, out, ws, ntok);
  router_finalize<<<1, 64, 0, stream>>>(ws, out, ntok);
}